// Round 2
// baseline (515.552 us; speedup 1.0000x reference)
//
#include <hip/hip_runtime.h>
#include <hip/hip_bf16.h>

#define N_NODES 20000
#define N_EDGES 40000
#define N_GRAPHS 500
#define D_IN 32
#define D_E 16
#define H1 100
#define H2 20
#define F1 50

#define ET1 64   // edges per block (lane = edge), layer-1 edge kernel
#define ET3 12   // edges per block, layer-2 edge kernel
#define YNT 64   // nodes per block, Y2 GEMM (lane = node)
#define YCT 68   // columns per block, Y2 GEMM (17 per wave, 5 col-blocks)

// ---------------------------------------------------------------------------
// Layer 1 edge messages, scalar-pipe weights:
//   msg[e,o] = sum_i x[src,i]*nn1b[i*100+o] + sum_{i,k} x[src,i]*ea[e,k]*nn1W[k,i*100+o]
// lanes = 64 edges; each wave owns 25 outputs; grid.y splits o into two halves.
// W addresses are wave-uniform (readfirstlane) -> s_load, FMA = v_fma(v,s,v).
// ---------------------------------------------------------------------------
__global__ __launch_bounds__(128) void edge1_kernel(
    const float* __restrict__ x, const float* __restrict__ ea,
    const int* __restrict__ eidx, const float* __restrict__ nn1W,
    const float* __restrict__ nn1b, float* __restrict__ agg1)
{
  __shared__ float sxT[D_IN][ET1];   // sxT[i][e] = x[src[e], i]

  const int tid  = threadIdx.x;
  const int lane = tid & 63;
  const int e0   = blockIdx.x * ET1;

  // stage x^T: thread t loads 16 of the 32 features of edge (t&63)'s src row
  {
    const int iq = (tid >> 6) * 16;
    const int s  = eidx[e0 + lane];
    const float4* xr = (const float4*)&x[s * D_IN + iq];
    float4 a = xr[0], b = xr[1], c = xr[2], d = xr[3];
    sxT[iq+ 0][lane] = a.x; sxT[iq+ 1][lane] = a.y; sxT[iq+ 2][lane] = a.z; sxT[iq+ 3][lane] = a.w;
    sxT[iq+ 4][lane] = b.x; sxT[iq+ 5][lane] = b.y; sxT[iq+ 6][lane] = b.z; sxT[iq+ 7][lane] = b.w;
    sxT[iq+ 8][lane] = c.x; sxT[iq+ 9][lane] = c.y; sxT[iq+10][lane] = c.z; sxT[iq+11][lane] = c.w;
    sxT[iq+12][lane] = d.x; sxT[iq+13][lane] = d.y; sxT[iq+14][lane] = d.z; sxT[iq+15][lane] = d.w;
  }

  // per-lane edge attributes in registers
  float se[D_E];
  {
    const float4* er = (const float4*)&ea[(size_t)(e0 + lane) * D_E];
    float4 a = er[0], b = er[1], c = er[2], d = er[3];
    se[ 0]=a.x; se[ 1]=a.y; se[ 2]=a.z; se[ 3]=a.w;
    se[ 4]=b.x; se[ 5]=b.y; se[ 6]=b.z; se[ 7]=b.w;
    se[ 8]=c.x; se[ 9]=c.y; se[10]=c.z; se[11]=c.w;
    se[12]=d.x; se[13]=d.y; se[14]=d.z; se[15]=d.w;
  }
  __syncthreads();

  // wave-uniform output-column base -> SGPR-resident W addressing
  const int obase = blockIdx.y * 50 + __builtin_amdgcn_readfirstlane(tid >> 6) * 25;
  const float* __restrict__ Wb = nn1W + obase;
  const float* __restrict__ Bb = nn1b + obase;

  float acc[25];
  #pragma unroll
  for (int og = 0; og < 25; ++og) acc[og] = 0.f;

  #pragma unroll 1
  for (int i = 0; i < D_IN; ++i) {
    const float xi = sxT[i][lane];
    // bias slice of theta
    #pragma unroll
    for (int og = 0; og < 25; ++og)
      acc[og] = fmaf(xi, Bb[i * H1 + og], acc[og]);
    #pragma unroll
    for (int k = 0; k < D_E; ++k) {
      const float pv = xi * se[k];
      const float* __restrict__ wrow = Wb + k * (D_IN * H1) + i * H1;
      #pragma unroll
      for (int og = 0; og < 25; ++og)
        acc[og] = fmaf(pv, wrow[og], acc[og]);
    }
  }

  const int d = eidx[N_EDGES + e0 + lane];
  float* ap = agg1 + (size_t)d * H1 + obase;
  #pragma unroll
  for (int og = 0; og < 25; ++og) atomicAdd(&ap[og], acc[og]);
}

// ---------------------------------------------------------------------------
// Node update 1: h1 = relu(agg1 + x @ root1 + bias1)
// ---------------------------------------------------------------------------
__global__ __launch_bounds__(128) void node1_kernel(
    const float* __restrict__ x, const float* __restrict__ agg1,
    const float* __restrict__ root1, const float* __restrict__ bias1,
    float* __restrict__ h1)
{
  __shared__ float sx[D_IN];
  const int n = blockIdx.x;
  const int o = threadIdx.x;
  if (o < D_IN) sx[o] = x[n * D_IN + o];
  __syncthreads();
  if (o < H1) {
    float v = agg1[n * H1 + o] + bias1[o];
    #pragma unroll
    for (int i = 0; i < D_IN; ++i) v = fmaf(sx[i], root1[i * H1 + o], v);
    h1[n * H1 + o] = fmaxf(v, 0.f);
  }
}

// ---------------------------------------------------------------------------
// Prepack Bext[i][j] (100 x 340): j=k*20+o -> k<16 ? W2[k,i*20+o] : b2[i*20+o]
// ---------------------------------------------------------------------------
__global__ __launch_bounds__(256) void prep_kernel(
    const float* __restrict__ nn2W, const float* __restrict__ nn2b,
    float* __restrict__ Bext)
{
  const int idx = blockIdx.x * 256 + threadIdx.x;
  if (idx < H1 * 340) {
    const int i = idx / 340, j = idx % 340;
    const int k = j / H2, o = j % H2;
    Bext[idx] = (k < 16) ? nn2W[k * (H1 * H2) + i * H2 + o] : nn2b[i * H2 + o];
  }
}

// ---------------------------------------------------------------------------
// Y2[n, j] = sum_i h1[n,i] * Bext[i, j]   (20000x100 @ 100x340)
// lanes = 64 nodes, wave owns 17 cols, scalar-pipe B reads, LDS-transposed store
// ---------------------------------------------------------------------------
__global__ __launch_bounds__(256) void y2_kernel(
    const float* __restrict__ h1, const float* __restrict__ Bext,
    float* __restrict__ Y2)
{
  __shared__ float hT[H1][YNT + 1];
  __shared__ float sy[YNT][YCT + 1];
  const int tid  = threadIdx.x;
  const int lane = tid & 63;
  const int n0   = blockIdx.x * YNT;
  const int cb   = blockIdx.y * YCT;

  for (int idx = tid; idx < YNT * H1; idx += 256) {
    const int nn = idx / H1, i = idx % H1;
    hT[i][nn] = (n0 + nn < N_NODES) ? h1[(size_t)(n0 + nn) * H1 + i] : 0.f;
  }
  __syncthreads();

  const int co = __builtin_amdgcn_readfirstlane(tid >> 6) * 17;
  const float* __restrict__ Bb = Bext + cb + co;

  float acc[17];
  #pragma unroll
  for (int c = 0; c < 17; ++c) acc[c] = 0.f;

  #pragma unroll 1
  for (int i = 0; i < H1; ++i) {
    const float hv = hT[i][lane];
    #pragma unroll
    for (int c = 0; c < 17; ++c)
      acc[c] = fmaf(hv, Bb[i * 340 + c], acc[c]);
  }

  #pragma unroll
  for (int c = 0; c < 17; ++c) sy[lane][co + c] = acc[c];
  __syncthreads();
  for (int idx = tid; idx < YNT * YCT; idx += 256) {
    const int r = idx / YCT, c = idx % YCT;
    if (n0 + r < N_NODES) Y2[(size_t)(n0 + r) * 340 + cb + c] = sy[r][c];
  }
}

// ---------------------------------------------------------------------------
// Layer 2 edge pass: msg2[e,o] = Y2[src,320+o] + sum_k ea[e,k]*Y2[src,k*20+o]
// ---------------------------------------------------------------------------
__global__ __launch_bounds__(256) void edge2_kernel(
    const float* __restrict__ ea, const int* __restrict__ eidx,
    const float* __restrict__ Y2, float* __restrict__ agg2)
{
  const int tid = threadIdx.x;
  const int el = tid / H2, o = tid % H2;
  const int e = blockIdx.x * ET3 + el;
  if (el < ET3 && e < N_EDGES) {
    const int s = eidx[e];
    const int d = eidx[N_EDGES + e];
    const float* yr = Y2 + (size_t)s * 340;
    float m = yr[320 + o];
    #pragma unroll
    for (int k = 0; k < D_E; ++k)
      m = fmaf(ea[e * D_E + k], yr[k * H2 + o], m);
    atomicAdd(&agg2[d * H2 + o], m);
  }
}

// ---------------------------------------------------------------------------
// Node update 2: h2 = relu(agg2 + h1 @ root2 + bias2)
// ---------------------------------------------------------------------------
__global__ __launch_bounds__(256) void node2_kernel(
    const float* __restrict__ h1, const float* __restrict__ agg2,
    const float* __restrict__ root2, const float* __restrict__ bias2,
    float* __restrict__ h2)
{
  const int tid = threadIdx.x;
  const int nl = tid / H2, o = tid % H2;
  const int n = blockIdx.x * ET3 + nl;
  if (nl < ET3 && n < N_NODES) {
    float v = agg2[n * H2 + o] + bias2[o];
    #pragma unroll 4
    for (int i = 0; i < H1; ++i)
      v = fmaf(h1[n * H1 + i], root2[i * H2 + o], v);
    h2[n * H2 + o] = fmaxf(v, 0.f);
  }
}

// ---------------------------------------------------------------------------
// Sum-pool readout: g[batch[n], o] += h2[n, o]
// ---------------------------------------------------------------------------
__global__ __launch_bounds__(256) void pool_kernel(
    const float* __restrict__ h2, const int* __restrict__ batch,
    float* __restrict__ g)
{
  const int idx = blockIdx.x * 256 + threadIdx.x;
  if (idx < N_NODES * H2) {
    const int n = idx / H2, o = idx % H2;
    atomicAdd(&g[batch[n] * H2 + o], h2[idx]);
  }
}

// ---------------------------------------------------------------------------
// Final MLP
// ---------------------------------------------------------------------------
__global__ __launch_bounds__(64) void final_kernel(
    const float* __restrict__ g, const float* __restrict__ lin1W,
    const float* __restrict__ lin1b, const float* __restrict__ lin2W,
    const float* __restrict__ lin2b, float* __restrict__ out)
{
  const int gr = blockIdx.x;
  const int t = threadIdx.x;
  float v = 0.f;
  if (t < F1) {
    float s = lin1b[t];
    #pragma unroll
    for (int o = 0; o < H2; ++o) s = fmaf(g[gr * H2 + o], lin1W[o * F1 + t], s);
    v = fmaxf(s, 0.f) * lin2W[t];
  }
  #pragma unroll
  for (int off = 32; off > 0; off >>= 1) v += __shfl_down(v, off, 64);
  if (t == 0) out[gr] = v + lin2b[0];
}

extern "C" void kernel_launch(void* const* d_in, const int* in_sizes, int n_in,
                              void* d_out, int out_size, void* d_ws, size_t ws_size,
                              hipStream_t stream) {
  const float* x     = (const float*)d_in[0];
  const float* ea    = (const float*)d_in[1];
  const int*   eidx  = (const int*)d_in[2];
  const int*   batch = (const int*)d_in[3];
  const float* nn1W  = (const float*)d_in[4];
  const float* nn1b  = (const float*)d_in[5];
  const float* root1 = (const float*)d_in[6];
  const float* bias1 = (const float*)d_in[7];
  const float* nn2W  = (const float*)d_in[8];
  const float* nn2b  = (const float*)d_in[9];
  const float* root2 = (const float*)d_in[10];
  const float* bias2 = (const float*)d_in[11];
  const float* lin1W = (const float*)d_in[12];
  const float* lin1b = (const float*)d_in[13];
  const float* lin2W = (const float*)d_in[14];
  const float* lin2b = (const float*)d_in[15];
  float* out = (float*)d_out;

  float* ws   = (float*)d_ws;
  float* agg1 = ws;                          // 2,000,000 floats
  float* agg2 = agg1 + N_NODES * H1;         //   400,000
  float* g    = agg2 + N_NODES * H2;         //    10,000
  float* h1   = g    + N_GRAPHS * H2;        // 2,000,000
  float* h2   = h1   + N_NODES * H1;         //   400,000
  float* Y2   = h2   + N_NODES * H2;         // 6,800,000
  float* Bext = h2;  // alias: Bext (34,000) consumed by y2 before node2 writes h2

  // zero the atomic accumulators (agg1 | agg2 | g are contiguous)
  hipMemsetAsync(agg1, 0, (size_t)(N_NODES * H1 + N_NODES * H2 + N_GRAPHS * H2) * sizeof(float), stream);

  prep_kernel<<<(H1 * 340 + 255) / 256, 256, 0, stream>>>(nn2W, nn2b, Bext);
  edge1_kernel<<<dim3(N_EDGES / ET1, 2), 128, 0, stream>>>(x, ea, eidx, nn1W, nn1b, agg1);
  node1_kernel<<<N_NODES, 128, 0, stream>>>(x, agg1, root1, bias1, h1);
  y2_kernel<<<dim3((N_NODES + YNT - 1) / YNT, 5), 256, 0, stream>>>(h1, Bext, Y2);
  edge2_kernel<<<(N_EDGES + ET3 - 1) / ET3, 256, 0, stream>>>(ea, eidx, Y2, agg2);
  node2_kernel<<<(N_NODES + ET3 - 1) / ET3, 256, 0, stream>>>(h1, agg2, root2, bias2, h2);
  pool_kernel<<<(N_NODES * H2 + 255) / 256, 256, 0, stream>>>(h2, batch, g);
  final_kernel<<<N_GRAPHS, 64, 0, stream>>>(g, lin1W, lin1b, lin2W, lin2b, out);
}

// Round 3
// 222.144 us; speedup vs baseline: 2.3208x; 2.3208x over previous
//
#include <hip/hip_runtime.h>
#include <hip/hip_bf16.h>
#include <hip/hip_fp16.h>

#define N_NODES 20000
#define N_EDGES 40000
#define N_GRAPHS 500
#define D_IN 32
#define D_E 16
#define H1 100
#define H2 20
#define F1 50

#define EB 128   // edges per block, MFMA edge1
#define YNB 64   // nodes per block, y2
#define ET3 12   // edges per block, layer-2 edge kernel

using h2f = __attribute__((ext_vector_type(2))) _Float16;
using h8f = __attribute__((ext_vector_type(8))) _Float16;
using f4  = __attribute__((ext_vector_type(4))) float;

// ---------------------------------------------------------------------------
// Pack W' into per-lane MFMA fragment order (fp16):
//   W'[jk = c*32+i][o] = (c<16 ? nn1W[c*3200 + i*100 + o] : nn1b[i*100+o]), o<100 else 0
//   Wfrag[((c*7 + to)*64 + l)*8 + j] = W'[c*32 + (l>>4)*8 + j][to*16 + (l&15)]
// ---------------------------------------------------------------------------
__global__ __launch_bounds__(256) void prep_w_kernel(
    const float* __restrict__ nn1W, const float* __restrict__ nn1b,
    unsigned short* __restrict__ Wfrag)
{
  const int tid = blockIdx.x * 256 + threadIdx.x;
  if (tid >= 544 * 112) return;
  const int c  = tid / 3584;          // 7*512
  const int r  = tid % 3584;
  const int to = r / 512;
  const int l  = (r % 512) >> 3;
  const int j  = r & 7;
  const int i  = (l >> 4) * 8 + j;    // row within chunk (= x feature index)
  const int o  = to * 16 + (l & 15);
  float v = 0.f;
  if (o < H1) v = (c < 16) ? nn1W[c * (D_IN * H1) + i * H1 + o] : nn1b[i * H1 + o];
  _Float16 hv = (_Float16)v;
  Wfrag[tid] = __builtin_bit_cast(unsigned short, hv);
}

// ---------------------------------------------------------------------------
// Layer 1 edge messages via fp16 MFMA:
//   msg[e,o] = sum_j P[e,j] * W'[j,o],  P[e, c*32+i] = ea[e,c]*x[src[e],i] (c=16: ea=1)
// Block: 256 thr = 4 waves, 128 edges. Wave w owns e-tiles {2w,2w+1} x 7 o-tiles.
// P is wave-private in LDS (no barriers in the K-loop).
// ---------------------------------------------------------------------------
__global__ __launch_bounds__(256) void edge1_kernel(
    const float* __restrict__ x, const float* __restrict__ ea,
    const int* __restrict__ eidx, const unsigned short* __restrict__ Wfrag,
    float* __restrict__ agg1)
{
  __shared__ uint4 Plds[8 * 64];   // [etile][lane] 16-B A-fragments
  __shared__ int   sdst[EB];

  const int t    = threadIdx.x;
  const int lane = t & 63;
  const int w    = t >> 6;
  const int e0   = blockIdx.x * EB;

  // ---- prologue: per-thread edge data (thread t owns edge t>>1, i-half t&1)
  const int e_loc = t >> 1;
  const int ih    = t & 1;
  const int ec    = min(e0 + e_loc, N_EDGES - 1);
  const int src   = eidx[ec];

  h2f xh[8];   // 16 fp16 x-features (this thread's i-half)
  {
    const float4* xp = (const float4*)&x[(size_t)src * D_IN + ih * 16];
    float4 v0 = xp[0], v1 = xp[1], v2 = xp[2], v3 = xp[3];
    float xf[16] = {v0.x,v0.y,v0.z,v0.w, v1.x,v1.y,v1.z,v1.w,
                    v2.x,v2.y,v2.z,v2.w, v3.x,v3.y,v3.z,v3.w};
    #pragma unroll
    for (int j = 0; j < 8; ++j) {
      h2f p; p[0] = (_Float16)xf[2*j]; p[1] = (_Float16)xf[2*j+1]; xh[j] = p;
    }
  }
  _Float16 eh[17];
  {
    const float4* ep = (const float4*)&ea[(size_t)ec * D_E];
    float4 v0 = ep[0], v1 = ep[1], v2 = ep[2], v3 = ep[3];
    float ef[16] = {v0.x,v0.y,v0.z,v0.w, v1.x,v1.y,v1.z,v1.w,
                    v2.x,v2.y,v2.z,v2.w, v3.x,v3.y,v3.z,v3.w};
    #pragma unroll
    for (int k = 0; k < 16; ++k) eh[k] = (_Float16)ef[k];
    eh[16] = (_Float16)1.0f;
  }
  if (t < EB) sdst[t] = eidx[N_EDGES + min(e0 + t, N_EDGES - 1)];
  __syncthreads();   // only barrier: publish sdst

  f4 acc[2][7];
  #pragma unroll
  for (int te = 0; te < 2; ++te)
    #pragma unroll
    for (int to = 0; to < 7; ++to)
      acc[te][to] = f4{0.f, 0.f, 0.f, 0.f};

  const uint4* __restrict__ Bf = (const uint4*)Wfrag;
  const int etw    = 2 * w;
  const int pbase  = (e_loc >> 4) * 64 + (e_loc & 15) + 16 * (2 * ih);

  #pragma unroll
  for (int c = 0; c < 17; ++c) {
    // B-fragments from global (L2-hot, 122 KB shared by all blocks)
    const uint4* bc = Bf + c * 448 + lane;
    uint4 b0 = bc[0*64], b1 = bc[1*64], b2 = bc[2*64], b3 = bc[3*64];
    uint4 b4 = bc[4*64], b5 = bc[5*64], b6 = bc[6*64];

    // P-generation: 16 fp16 products via pk_mul, two 16-B frag writes
    h2f es; es[0] = eh[c]; es[1] = eh[c];
    unsigned int pk[8];
    #pragma unroll
    for (int j = 0; j < 8; ++j) {
      h2f pr = xh[j] * es;
      pk[j] = __builtin_bit_cast(unsigned int, pr);
    }
    Plds[pbase]      = make_uint4(pk[0], pk[1], pk[2], pk[3]);
    Plds[pbase + 16] = make_uint4(pk[4], pk[5], pk[6], pk[7]);

    // A-fragments: own-wave LDS (lgkmcnt ordering, wave-synchronous)
    uint4 a0 = Plds[ etw      * 64 + lane];
    uint4 a1 = Plds[(etw + 1) * 64 + lane];
    h8f A0 = __builtin_bit_cast(h8f, a0);
    h8f A1 = __builtin_bit_cast(h8f, a1);

    uint4 bb[7] = {b0, b1, b2, b3, b4, b5, b6};
    #pragma unroll
    for (int to = 0; to < 7; ++to) {
      h8f B = __builtin_bit_cast(h8f, bb[to]);
      acc[0][to] = __builtin_amdgcn_mfma_f32_16x16x32_f16(A0, B, acc[0][to], 0, 0, 0);
      acc[1][to] = __builtin_amdgcn_mfma_f32_16x16x32_f16(A1, B, acc[1][to], 0, 0, 0);
    }
  }

  // ---- epilogue: coalesced atomics (lanes 0..15 = 16 consecutive o)
  const int col = lane & 15, rowg = lane >> 4;
  #pragma unroll
  for (int te = 0; te < 2; ++te) {
    #pragma unroll
    for (int r = 0; r < 4; ++r) {
      const int el = (etw + te) * 16 + rowg * 4 + r;
      if (e0 + el < N_EDGES) {
        const int d = sdst[el];
        float* ap = agg1 + (size_t)d * H1;
        #pragma unroll
        for (int to = 0; to < 7; ++to) {
          const int o = to * 16 + col;
          if (o < H1) atomicAdd(&ap[o], acc[te][to][r]);
        }
      }
    }
  }
}

// ---------------------------------------------------------------------------
// Node update 1: h1 = relu(agg1 + x @ root1 + bias1)
// ---------------------------------------------------------------------------
__global__ __launch_bounds__(128) void node1_kernel(
    const float* __restrict__ x, const float* __restrict__ agg1,
    const float* __restrict__ root1, const float* __restrict__ bias1,
    float* __restrict__ h1)
{
  __shared__ float sx[D_IN];
  const int n = blockIdx.x;
  const int o = threadIdx.x;
  if (o < D_IN) sx[o] = x[n * D_IN + o];
  __syncthreads();
  if (o < H1) {
    float v = agg1[n * H1 + o] + bias1[o];
    #pragma unroll
    for (int i = 0; i < D_IN; ++i) v = fmaf(sx[i], root1[i * H1 + o], v);
    h1[n * H1 + o] = fmaxf(v, 0.f);
  }
}

// ---------------------------------------------------------------------------
// Prepack Bext[i][j] (100 x 340): j=k*20+o -> k<16 ? W2[k,i*20+o] : b2[i*20+o]
// ---------------------------------------------------------------------------
__global__ __launch_bounds__(256) void prep_b_kernel(
    const float* __restrict__ nn2W, const float* __restrict__ nn2b,
    float* __restrict__ Bext)
{
  const int idx = blockIdx.x * 256 + threadIdx.x;
  if (idx < H1 * 340) {
    const int i = idx / 340, j = idx % 340;
    const int k = j / H2, o = j % H2;
    Bext[idx] = (k < 16) ? nn2W[k * (H1 * H2) + i * H2 + o] : nn2b[i * H2 + o];
  }
}

// ---------------------------------------------------------------------------
// Y2[n, j] = sum_i h1[n,i] * Bext[i, j]   (20000x100 @ 100x340), fp32
// thread owns 4 j x 16 n  => 16 FMA per ds_read_b128 (VALU-bound)
// ---------------------------------------------------------------------------
__global__ __launch_bounds__(384) void y2_kernel(
    const float* __restrict__ h1, const float* __restrict__ Bext,
    float* __restrict__ Y2)
{
  __shared__ float hT[H1][YNB + 4];   // stride 68 floats: 16-B aligned rows
  const int t  = threadIdx.x;
  const int n0 = blockIdx.x * YNB;

  for (int idx = t; idx < YNB * H1; idx += 384) {
    const int nn = idx / H1, i = idx - nn * H1;
    const int n = n0 + nn;
    hT[i][nn] = (n < N_NODES) ? h1[(size_t)n * H1 + i] : 0.f;
  }
  __syncthreads();

  if (t < 340) {
    const int jg = t % 85, ng = t / 85;   // lanes contiguous in jg -> coalesced stores
    const int j0 = jg * 4;
    const float* __restrict__ bp = Bext + j0;

    float acc[4][16];
    #pragma unroll
    for (int j = 0; j < 4; ++j)
      #pragma unroll
      for (int n = 0; n < 16; ++n) acc[j][n] = 0.f;

    #pragma unroll 2
    for (int i = 0; i < H1; ++i) {
      const float4 bv = *(const float4*)&bp[i * 340];
      const float4* hp = (const float4*)&hT[i][ng * 16];
      float hv[16];
      *(float4*)&hv[0]  = hp[0];
      *(float4*)&hv[4]  = hp[1];
      *(float4*)&hv[8]  = hp[2];
      *(float4*)&hv[12] = hp[3];
      #pragma unroll
      for (int n = 0; n < 16; ++n) {
        acc[0][n] = fmaf(hv[n], bv.x, acc[0][n]);
        acc[1][n] = fmaf(hv[n], bv.y, acc[1][n]);
        acc[2][n] = fmaf(hv[n], bv.z, acc[2][n]);
        acc[3][n] = fmaf(hv[n], bv.w, acc[3][n]);
      }
    }
    #pragma unroll
    for (int n = 0; n < 16; ++n) {
      const int nn = n0 + ng * 16 + n;
      if (nn < N_NODES)
        *(float4*)&Y2[(size_t)nn * 340 + j0] =
            make_float4(acc[0][n], acc[1][n], acc[2][n], acc[3][n]);
    }
  }
}

// ---------------------------------------------------------------------------
// Layer 2 edge pass: msg2[e,o] = Y2[src,320+o] + sum_k ea[e,k]*Y2[src,k*20+o]
// ---------------------------------------------------------------------------
__global__ __launch_bounds__(256) void edge2_kernel(
    const float* __restrict__ ea, const int* __restrict__ eidx,
    const float* __restrict__ Y2, float* __restrict__ agg2)
{
  const int tid = threadIdx.x;
  const int el = tid / H2, o = tid % H2;
  const int e = blockIdx.x * ET3 + el;
  if (el < ET3 && e < N_EDGES) {
    const int s = eidx[e];
    const int d = eidx[N_EDGES + e];
    const float* yr = Y2 + (size_t)s * 340;
    float m = yr[320 + o];
    #pragma unroll
    for (int k = 0; k < D_E; ++k)
      m = fmaf(ea[e * D_E + k], yr[k * H2 + o], m);
    atomicAdd(&agg2[d * H2 + o], m);
  }
}

// ---------------------------------------------------------------------------
// Node update 2: h2 = relu(agg2 + h1 @ root2 + bias2)
// ---------------------------------------------------------------------------
__global__ __launch_bounds__(256) void node2_kernel(
    const float* __restrict__ h1, const float* __restrict__ agg2,
    const float* __restrict__ root2, const float* __restrict__ bias2,
    float* __restrict__ h2)
{
  const int tid = threadIdx.x;
  const int nl = tid / H2, o = tid % H2;
  const int n = blockIdx.x * ET3 + nl;
  if (nl < ET3 && n < N_NODES) {
    float v = agg2[n * H2 + o] + bias2[o];
    #pragma unroll 4
    for (int i = 0; i < H1; ++i)
      v = fmaf(h1[n * H1 + i], root2[i * H2 + o], v);
    h2[n * H2 + o] = fmaxf(v, 0.f);
  }
}

// ---------------------------------------------------------------------------
// Sum-pool readout: g[batch[n], o] += h2[n, o]
// ---------------------------------------------------------------------------
__global__ __launch_bounds__(256) void pool_kernel(
    const float* __restrict__ h2, const int* __restrict__ batch,
    float* __restrict__ g)
{
  const int idx = blockIdx.x * 256 + threadIdx.x;
  if (idx < N_NODES * H2) {
    const int n = idx / H2, o = idx % H2;
    atomicAdd(&g[batch[n] * H2 + o], h2[idx]);
  }
}

// ---------------------------------------------------------------------------
// Final MLP
// ---------------------------------------------------------------------------
__global__ __launch_bounds__(64) void final_kernel(
    const float* __restrict__ g, const float* __restrict__ lin1W,
    const float* __restrict__ lin1b, const float* __restrict__ lin2W,
    const float* __restrict__ lin2b, float* __restrict__ out)
{
  const int gr = blockIdx.x;
  const int tt = threadIdx.x;
  float v = 0.f;
  if (tt < F1) {
    float s = lin1b[tt];
    #pragma unroll
    for (int o = 0; o < H2; ++o) s = fmaf(g[gr * H2 + o], lin1W[o * F1 + tt], s);
    v = fmaxf(s, 0.f) * lin2W[tt];
  }
  #pragma unroll
  for (int off = 32; off > 0; off >>= 1) v += __shfl_down(v, off, 64);
  if (tt == 0) out[gr] = v + lin2b[0];
}

extern "C" void kernel_launch(void* const* d_in, const int* in_sizes, int n_in,
                              void* d_out, int out_size, void* d_ws, size_t ws_size,
                              hipStream_t stream) {
  const float* x     = (const float*)d_in[0];
  const float* ea    = (const float*)d_in[1];
  const int*   eidx  = (const int*)d_in[2];
  const int*   batch = (const int*)d_in[3];
  const float* nn1W  = (const float*)d_in[4];
  const float* nn1b  = (const float*)d_in[5];
  const float* root1 = (const float*)d_in[6];
  const float* bias1 = (const float*)d_in[7];
  const float* nn2W  = (const float*)d_in[8];
  const float* nn2b  = (const float*)d_in[9];
  const float* root2 = (const float*)d_in[10];
  const float* bias2 = (const float*)d_in[11];
  const float* lin1W = (const float*)d_in[12];
  const float* lin1b = (const float*)d_in[13];
  const float* lin2W = (const float*)d_in[14];
  const float* lin2b = (const float*)d_in[15];
  float* out = (float*)d_out;

  float* ws   = (float*)d_ws;
  float* agg1 = ws;                          // 2,000,000 floats
  float* agg2 = agg1 + N_NODES * H1;         //   400,000
  float* g    = agg2 + N_NODES * H2;         //    10,000
  float* h1   = g    + N_GRAPHS * H2;        // 2,000,000
  float* h2   = h1   + N_NODES * H1;         //   400,000
  float* Y2   = h2   + N_NODES * H2;         // 6,800,000
  // aliases (consumed before their hosts are written):
  float* Bext = h2;                                          // 34,000 < 400,000
  unsigned short* Wfrag = (unsigned short*)(Y2 + (size_t)N_NODES * 340 - 30464);

  // zero the atomic accumulators (agg1 | agg2 | g are contiguous)
  hipMemsetAsync(agg1, 0,
      (size_t)(N_NODES * H1 + N_NODES * H2 + N_GRAPHS * H2) * sizeof(float), stream);

  prep_w_kernel<<<(544 * 112 + 255) / 256, 256, 0, stream>>>(nn1W, nn1b, Wfrag);
  prep_b_kernel<<<(H1 * 340 + 255) / 256, 256, 0, stream>>>(nn2W, nn2b, Bext);
  edge1_kernel<<<(N_EDGES + EB - 1) / EB, 256, 0, stream>>>(x, ea, eidx, Wfrag, agg1);
  node1_kernel<<<N_NODES, 128, 0, stream>>>(x, agg1, root1, bias1, h1);
  y2_kernel<<<(N_NODES + YNB - 1) / YNB, 384, 0, stream>>>(h1, Bext, Y2);
  edge2_kernel<<<(N_EDGES + ET3 - 1) / ET3, 256, 0, stream>>>(ea, eidx, Y2, agg2);
  node2_kernel<<<(N_NODES + ET3 - 1) / ET3, 256, 0, stream>>>(h1, agg2, root2, bias2, h2);
  pool_kernel<<<(N_NODES * H2 + 255) / 256, 256, 0, stream>>>(h2, batch, g);
  final_kernel<<<N_GRAPHS, 64, 0, stream>>>(g, lin1W, lin1b, lin2W, lin2b, out);
}

// Round 4
// 201.772 us; speedup vs baseline: 2.5551x; 1.1010x over previous
//
#include <hip/hip_runtime.h>
#include <hip/hip_bf16.h>
#include <hip/hip_fp16.h>

#define N_NODES 20000
#define N_EDGES 40000
#define N_GRAPHS 500
#define D_IN 32
#define D_E 16
#define H1 100
#define H2 20
#define F1 50

#define EB 128    // edges per block, MFMA edge1
#define YNB 12    // nodes per block, y2
#define ET3 12    // edges/nodes per block, layer-2 kernels

using h2f = __attribute__((ext_vector_type(2))) _Float16;
using h8f = __attribute__((ext_vector_type(8))) _Float16;
using f4  = __attribute__((ext_vector_type(4))) float;

// ---------------------------------------------------------------------------
// Merged prep: (a) W' -> per-lane MFMA fragment order (fp16)
//   W'[c*32+i][o] = (c<16 ? nn1W[c*3200+i*100+o] : nn1b[i*100+o]), o<100 else 0
//   Wfrag[((c*7+to)*64+l)*8+j] = W'[c*32+(l>>4)*8+j][to*16+(l&15)]
// (b) Bext[i][j] (100 x 340): j=k*20+o -> k<16 ? W2[k,i*20+o] : b2[i*20+o]
// ---------------------------------------------------------------------------
__global__ __launch_bounds__(256) void prep_kernel(
    const float* __restrict__ nn1W, const float* __restrict__ nn1b,
    const float* __restrict__ nn2W, const float* __restrict__ nn2b,
    unsigned short* __restrict__ Wfrag, float* __restrict__ Bext)
{
  const int tid = blockIdx.x * 256 + threadIdx.x;
  if (tid < 544 * 112) {
    const int c  = tid / 3584;
    const int r  = tid % 3584;
    const int to = r / 512;
    const int l  = (r % 512) >> 3;
    const int j  = r & 7;
    const int i  = (l >> 4) * 8 + j;
    const int o  = to * 16 + (l & 15);
    float v = 0.f;
    if (o < H1) v = (c < 16) ? nn1W[c * (D_IN * H1) + i * H1 + o] : nn1b[i * H1 + o];
    _Float16 hv = (_Float16)v;
    Wfrag[tid] = __builtin_bit_cast(unsigned short, hv);
  } else {
    const int idx = tid - 544 * 112;
    if (idx < H1 * 340) {
      const int i = idx / 340, j = idx % 340;
      const int k = j / H2, o = j % H2;
      Bext[idx] = (k < 16) ? nn2W[k * (H1 * H2) + i * H2 + o] : nn2b[i * H2 + o];
    }
  }
}

// ---------------------------------------------------------------------------
// Layer 1 edge messages via fp16 MFMA (unchanged from round 3):
//   msg[e,o] = sum_j P[e,j]*W'[j,o],  P[e,c*32+i] = ea[e,c]*x[src[e],i] (c=16: ea=1)
// ---------------------------------------------------------------------------
__global__ __launch_bounds__(256) void edge1_kernel(
    const float* __restrict__ x, const float* __restrict__ ea,
    const int* __restrict__ eidx, const unsigned short* __restrict__ Wfrag,
    float* __restrict__ agg1)
{
  __shared__ uint4 Plds[8 * 64];
  __shared__ int   sdst[EB];

  const int t    = threadIdx.x;
  const int lane = t & 63;
  const int w    = t >> 6;
  const int e0   = blockIdx.x * EB;

  const int e_loc = t >> 1;
  const int ih    = t & 1;
  const int ec    = min(e0 + e_loc, N_EDGES - 1);
  const int src   = eidx[ec];

  h2f xh[8];
  {
    const float4* xp = (const float4*)&x[(size_t)src * D_IN + ih * 16];
    float4 v0 = xp[0], v1 = xp[1], v2 = xp[2], v3 = xp[3];
    float xf[16] = {v0.x,v0.y,v0.z,v0.w, v1.x,v1.y,v1.z,v1.w,
                    v2.x,v2.y,v2.z,v2.w, v3.x,v3.y,v3.z,v3.w};
    #pragma unroll
    for (int j = 0; j < 8; ++j) {
      h2f p; p[0] = (_Float16)xf[2*j]; p[1] = (_Float16)xf[2*j+1]; xh[j] = p;
    }
  }
  _Float16 eh[17];
  {
    const float4* ep = (const float4*)&ea[(size_t)ec * D_E];
    float4 v0 = ep[0], v1 = ep[1], v2 = ep[2], v3 = ep[3];
    float ef[16] = {v0.x,v0.y,v0.z,v0.w, v1.x,v1.y,v1.z,v1.w,
                    v2.x,v2.y,v2.z,v2.w, v3.x,v3.y,v3.z,v3.w};
    #pragma unroll
    for (int k = 0; k < 16; ++k) eh[k] = (_Float16)ef[k];
    eh[16] = (_Float16)1.0f;
  }
  if (t < EB) sdst[t] = eidx[N_EDGES + min(e0 + t, N_EDGES - 1)];
  __syncthreads();

  f4 acc[2][7];
  #pragma unroll
  for (int te = 0; te < 2; ++te)
    #pragma unroll
    for (int to = 0; to < 7; ++to)
      acc[te][to] = f4{0.f, 0.f, 0.f, 0.f};

  const uint4* __restrict__ Bf = (const uint4*)Wfrag;
  const int etw   = 2 * w;
  const int pbase = (e_loc >> 4) * 64 + (e_loc & 15) + 16 * (2 * ih);

  #pragma unroll
  for (int c = 0; c < 17; ++c) {
    const uint4* bc = Bf + c * 448 + lane;
    uint4 b0 = bc[0*64], b1 = bc[1*64], b2 = bc[2*64], b3 = bc[3*64];
    uint4 b4 = bc[4*64], b5 = bc[5*64], b6 = bc[6*64];

    h2f es; es[0] = eh[c]; es[1] = eh[c];
    unsigned int pk[8];
    #pragma unroll
    for (int j = 0; j < 8; ++j) {
      h2f pr = xh[j] * es;
      pk[j] = __builtin_bit_cast(unsigned int, pr);
    }
    Plds[pbase]      = make_uint4(pk[0], pk[1], pk[2], pk[3]);
    Plds[pbase + 16] = make_uint4(pk[4], pk[5], pk[6], pk[7]);

    uint4 a0 = Plds[ etw      * 64 + lane];
    uint4 a1 = Plds[(etw + 1) * 64 + lane];
    h8f A0 = __builtin_bit_cast(h8f, a0);
    h8f A1 = __builtin_bit_cast(h8f, a1);

    uint4 bb[7] = {b0, b1, b2, b3, b4, b5, b6};
    #pragma unroll
    for (int to = 0; to < 7; ++to) {
      h8f B = __builtin_bit_cast(h8f, bb[to]);
      acc[0][to] = __builtin_amdgcn_mfma_f32_16x16x32_f16(A0, B, acc[0][to], 0, 0, 0);
      acc[1][to] = __builtin_amdgcn_mfma_f32_16x16x32_f16(A1, B, acc[1][to], 0, 0, 0);
    }
  }

  const int col = lane & 15, rowg = lane >> 4;
  #pragma unroll
  for (int te = 0; te < 2; ++te) {
    #pragma unroll
    for (int r = 0; r < 4; ++r) {
      const int el = (etw + te) * 16 + rowg * 4 + r;
      if (e0 + el < N_EDGES) {
        const int d = sdst[el];
        float* ap = agg1 + (size_t)d * H1;
        #pragma unroll
        for (int to = 0; to < 7; ++to) {
          const int o = to * 16 + col;
          if (o < H1) atomicAdd(&ap[o], acc[te][to][r]);
        }
      }
    }
  }
}

// ---------------------------------------------------------------------------
// Node update 1: h1 = relu(agg1 + x @ root1 + bias1)
// ---------------------------------------------------------------------------
__global__ __launch_bounds__(128) void node1_kernel(
    const float* __restrict__ x, const float* __restrict__ agg1,
    const float* __restrict__ root1, const float* __restrict__ bias1,
    float* __restrict__ h1)
{
  __shared__ float sx[D_IN];
  const int n = blockIdx.x;
  const int o = threadIdx.x;
  if (o < D_IN) sx[o] = x[n * D_IN + o];
  __syncthreads();
  if (o < H1) {
    float v = agg1[n * H1 + o] + bias1[o];
    #pragma unroll
    for (int i = 0; i < D_IN; ++i) v = fmaf(sx[i], root1[i * H1 + o], v);
    h1[n * H1 + o] = fmaxf(v, 0.f);
  }
}

// ---------------------------------------------------------------------------
// Y2[n, j] = sum_i h1[n,i] * Bext[i, j]   (20000x100 @ 100x340), fp32
// thread owns 4n x 4j = 16 acc (fits registers); block = 12 nodes x 340 cols
// ---------------------------------------------------------------------------
__global__ __launch_bounds__(256) void y2_kernel(
    const float* __restrict__ h1, const float* __restrict__ Bext,
    float* __restrict__ Y2)
{
  __shared__ __align__(16) float hT[H1][YNB];   // row stride 48 B (16B-aligned)
  const int t  = threadIdx.x;
  const int n0 = blockIdx.x * YNB;

  for (int idx = t; idx < YNB * H1; idx += 256) {
    const int nn = idx / H1, i = idx - nn * H1;
    const int n = n0 + nn;
    hT[i][nn] = (n < N_NODES) ? h1[(size_t)n * H1 + i] : 0.f;
  }
  __syncthreads();

  const int jg = t % 85;     // j0 = 4*jg : lanes contiguous in j -> coalesced
  const int ng = t / 85;     // 0..2 active (t=255 idle)
  if (ng < 3) {
    const int j0 = jg * 4;
    const float* __restrict__ bp = Bext + j0;
    float acc[4][4];
    #pragma unroll
    for (int r = 0; r < 4; ++r)
      #pragma unroll
      for (int c = 0; c < 4; ++c) acc[r][c] = 0.f;

    #pragma unroll 2
    for (int i = 0; i < H1; ++i) {
      const float4 bv = *(const float4*)&bp[i * 340];
      const float4 hv = *(const float4*)&hT[i][ng * 4];   // broadcast read
      acc[0][0] = fmaf(hv.x, bv.x, acc[0][0]);
      acc[0][1] = fmaf(hv.x, bv.y, acc[0][1]);
      acc[0][2] = fmaf(hv.x, bv.z, acc[0][2]);
      acc[0][3] = fmaf(hv.x, bv.w, acc[0][3]);
      acc[1][0] = fmaf(hv.y, bv.x, acc[1][0]);
      acc[1][1] = fmaf(hv.y, bv.y, acc[1][1]);
      acc[1][2] = fmaf(hv.y, bv.z, acc[1][2]);
      acc[1][3] = fmaf(hv.y, bv.w, acc[1][3]);
      acc[2][0] = fmaf(hv.z, bv.x, acc[2][0]);
      acc[2][1] = fmaf(hv.z, bv.y, acc[2][1]);
      acc[2][2] = fmaf(hv.z, bv.z, acc[2][2]);
      acc[2][3] = fmaf(hv.z, bv.w, acc[2][3]);
      acc[3][0] = fmaf(hv.w, bv.x, acc[3][0]);
      acc[3][1] = fmaf(hv.w, bv.y, acc[3][1]);
      acc[3][2] = fmaf(hv.w, bv.z, acc[3][2]);
      acc[3][3] = fmaf(hv.w, bv.w, acc[3][3]);
    }
    const int nb = n0 + ng * 4;
    #pragma unroll
    for (int r = 0; r < 4; ++r) {
      const int n = nb + r;
      if (n < N_NODES)
        *(float4*)&Y2[(size_t)n * 340 + j0] =
            make_float4(acc[r][0], acc[r][1], acc[r][2], acc[r][3]);
    }
  }
}

// ---------------------------------------------------------------------------
// Layer 2 edge pass with LDS row staging:
//   msg2[e,o] = Y2[src,320+o] + sum_k ea[e,k]*Y2[src,k*20+o]
// ---------------------------------------------------------------------------
__global__ __launch_bounds__(256) void edge2_kernel(
    const float* __restrict__ ea, const int* __restrict__ eidx,
    const float* __restrict__ Y2, float* __restrict__ agg2)
{
  __shared__ __align__(16) float sy[ET3][344];
  __shared__ float se[ET3][16];
  __shared__ int sd[ET3];
  const int t  = threadIdx.x;
  const int e0 = blockIdx.x * ET3;

  if (t < ET3) {
    const int e = e0 + t;
    sd[t] = (e < N_EDGES) ? eidx[N_EDGES + e] : -1;
  }
  for (int idx = t; idx < ET3 * 4; idx += 256) {   // 12 x 16 ea floats as float4
    const int el = idx >> 2, q = idx & 3;
    const int e = e0 + el;
    if (e < N_EDGES)
      *(float4*)&se[el][q * 4] = *(const float4*)&ea[(size_t)e * D_E + q * 4];
  }
  for (int idx = t; idx < ET3 * 85; idx += 256) {  // 12 rows x 85 float4
    const int el = idx / 85, q = idx - el * 85;
    const int e = e0 + el;
    if (e < N_EDGES) {
      const int s = eidx[e];
      *(float4*)&sy[el][q * 4] = *(const float4*)&Y2[(size_t)s * 340 + q * 4];
    }
  }
  __syncthreads();

  const int el = t / H2, o = t % H2;
  const int e = e0 + el;
  if (el < ET3 && e < N_EDGES) {
    float m = sy[el][320 + o];
    #pragma unroll
    for (int k = 0; k < D_E; ++k)
      m = fmaf(se[el][k], sy[el][k * 20 + o], m);
    atomicAdd(&agg2[(size_t)sd[el] * H2 + o], m);
  }
}

// ---------------------------------------------------------------------------
// Fused node update 2 + sum-pool:
//   v = relu(agg2 + h1 @ root2 + bias2); run-length reduce rows by graph id
//   (batch is sorted), then ~2x20 atomics per block into g
// ---------------------------------------------------------------------------
__global__ __launch_bounds__(256) void node2_pool_kernel(
    const float* __restrict__ h1, const float* __restrict__ agg2,
    const float* __restrict__ root2, const float* __restrict__ bias2,
    const int* __restrict__ batch, float* __restrict__ g)
{
  __shared__ float sroot[H1 * H2];
  __shared__ float sv[ET3][H2];
  __shared__ int   sg[ET3];
  const int t  = threadIdx.x;
  const int n0 = blockIdx.x * ET3;

  for (int idx = t; idx < (H1 * H2) / 4; idx += 256)
    *(float4*)&sroot[idx * 4] = *(const float4*)&root2[idx * 4];
  if (t < ET3) {
    const int n = n0 + t;
    sg[t] = (n < N_NODES) ? batch[n] : -1;
  }
  __syncthreads();

  const int nl = t / H2, o = t % H2;
  const int n = n0 + nl;
  if (nl < ET3) {
    float v = 0.f;
    if (n < N_NODES) {
      v = agg2[(size_t)n * H2 + o] + bias2[o];
      const float* hr = &h1[(size_t)n * H1];
      #pragma unroll 5
      for (int i = 0; i < H1; i += 4) {
        const float4 hv = *(const float4*)&hr[i];
        v = fmaf(hv.x, sroot[(i    ) * H2 + o], v);
        v = fmaf(hv.y, sroot[(i + 1) * H2 + o], v);
        v = fmaf(hv.z, sroot[(i + 2) * H2 + o], v);
        v = fmaf(hv.w, sroot[(i + 3) * H2 + o], v);
      }
      v = fmaxf(v, 0.f);
    }
    sv[nl][o] = v;
  }
  __syncthreads();

  if (t < H2) {
    float run = 0.f;
    int cur = sg[0];
    #pragma unroll
    for (int r = 0; r < ET3; ++r) {
      const int gid = sg[r];
      if (gid != cur) {
        if (cur >= 0) atomicAdd(&g[cur * H2 + t], run);
        run = 0.f; cur = gid;
      }
      run += sv[r][t];
    }
    if (cur >= 0) atomicAdd(&g[cur * H2 + t], run);
  }
}

// ---------------------------------------------------------------------------
// Final MLP
// ---------------------------------------------------------------------------
__global__ __launch_bounds__(64) void final_kernel(
    const float* __restrict__ g, const float* __restrict__ lin1W,
    const float* __restrict__ lin1b, const float* __restrict__ lin2W,
    const float* __restrict__ lin2b, float* __restrict__ out)
{
  const int gr = blockIdx.x;
  const int tt = threadIdx.x;
  float v = 0.f;
  if (tt < F1) {
    float s = lin1b[tt];
    #pragma unroll
    for (int o = 0; o < H2; ++o) s = fmaf(g[gr * H2 + o], lin1W[o * F1 + tt], s);
    v = fmaxf(s, 0.f) * lin2W[tt];
  }
  #pragma unroll
  for (int off = 32; off > 0; off >>= 1) v += __shfl_down(v, off, 64);
  if (tt == 0) out[gr] = v + lin2b[0];
}

extern "C" void kernel_launch(void* const* d_in, const int* in_sizes, int n_in,
                              void* d_out, int out_size, void* d_ws, size_t ws_size,
                              hipStream_t stream) {
  const float* x     = (const float*)d_in[0];
  const float* ea    = (const float*)d_in[1];
  const int*   eidx  = (const int*)d_in[2];
  const int*   batch = (const int*)d_in[3];
  const float* nn1W  = (const float*)d_in[4];
  const float* nn1b  = (const float*)d_in[5];
  const float* root1 = (const float*)d_in[6];
  const float* bias1 = (const float*)d_in[7];
  const float* nn2W  = (const float*)d_in[8];
  const float* nn2b  = (const float*)d_in[9];
  const float* root2 = (const float*)d_in[10];
  const float* bias2 = (const float*)d_in[11];
  const float* lin1W = (const float*)d_in[12];
  const float* lin1b = (const float*)d_in[13];
  const float* lin2W = (const float*)d_in[14];
  const float* lin2b = (const float*)d_in[15];
  float* out = (float*)d_out;

  float* ws   = (float*)d_ws;
  float* agg1 = ws;                          // 2,000,000 floats
  float* agg2 = agg1 + N_NODES * H1;         //   400,000
  float* g    = agg2 + N_NODES * H2;         //    10,000
  float* h1   = g    + N_GRAPHS * H2;        // 2,000,000
  float* spare= h1   + N_NODES * H1;         //   400,000 (old h2 slot)
  float* Y2   = spare+ N_NODES * H2;         // 6,800,000
  // aliases (consumed before their hosts are written):
  float* Bext = spare;                                       // 34,000 < 400,000
  unsigned short* Wfrag = (unsigned short*)(Y2 + (size_t)N_NODES * 340 - 30464);

  // zero the atomic accumulators (agg1 | agg2 | g are contiguous)
  hipMemsetAsync(agg1, 0,
      (size_t)(N_NODES * H1 + N_NODES * H2 + N_GRAPHS * H2) * sizeof(float), stream);

  prep_kernel<<<(544 * 112 + H1 * 340 + 255) / 256, 256, 0, stream>>>(
      nn1W, nn1b, nn2W, nn2b, Wfrag, Bext);
  edge1_kernel<<<(N_EDGES + EB - 1) / EB, 256, 0, stream>>>(x, ea, eidx, Wfrag, agg1);
  node1_kernel<<<N_NODES, 128, 0, stream>>>(x, agg1, root1, bias1, h1);
  y2_kernel<<<(N_NODES + YNB - 1) / YNB, 256, 0, stream>>>(h1, Bext, Y2);
  edge2_kernel<<<(N_EDGES + ET3 - 1) / ET3, 256, 0, stream>>>(ea, eidx, Y2, agg2);
  node2_pool_kernel<<<(N_NODES + ET3 - 1) / ET3, 256, 0, stream>>>(
      h1, agg2, root2, bias2, batch, g);
  final_kernel<<<N_GRAPHS, 64, 0, stream>>>(g, lin1W, lin1b, lin2W, lin2b, out);
}

// Round 5
// 182.723 us; speedup vs baseline: 2.8215x; 1.1042x over previous
//
#include <hip/hip_runtime.h>
#include <hip/hip_bf16.h>
#include <hip/hip_fp16.h>

#define N_NODES 20000
#define N_EDGES 40000
#define N_GRAPHS 500
#define D_IN 32
#define D_E 16
#define H1 100
#define H2 20
#define F1 50

#define EB1 64    // edges per block, MFMA edge1
#define YNB 12    // nodes per block, y2h1
#define ET3 12    // edges/nodes per block, layer-2 kernels

using h2f = __attribute__((ext_vector_type(2))) _Float16;
using h8f = __attribute__((ext_vector_type(8))) _Float16;
using f4  = __attribute__((ext_vector_type(4))) float;

// ---------------------------------------------------------------------------
// Merged prep: (a) W' -> per-lane MFMA fragment order (fp16)
//   W'[c*32+i][o] = (c<16 ? nn1W[c*3200+i*100+o] : nn1b[i*100+o]), o<100 else 0
//   Wfrag[((c*7+to)*64+l)*8+j] = W'[c*32+(l>>4)*8+j][to*16+(l&15)]
// (b) Bext[i][j] (100x340): j=k*20+o -> k<16 ? W2[k,i*20+o] : b2[i*20+o]
// (c) zero agg1|agg2|g (2,410,000 floats, contiguous) via grid-stride float4
// ---------------------------------------------------------------------------
__global__ __launch_bounds__(256) void prep_kernel(
    const float* __restrict__ nn1W, const float* __restrict__ nn1b,
    const float* __restrict__ nn2W, const float* __restrict__ nn2b,
    unsigned short* __restrict__ Wfrag, float* __restrict__ Bext,
    float* __restrict__ zbase)
{
  const int tid = blockIdx.x * 256 + threadIdx.x;
  if (tid < 544 * 112) {
    const int c  = tid / 3584;
    const int r  = tid % 3584;
    const int to = r / 512;
    const int l  = (r % 512) >> 3;
    const int j  = r & 7;
    const int i  = (l >> 4) * 8 + j;
    const int o  = to * 16 + (l & 15);
    float v = 0.f;
    if (o < H1) v = (c < 16) ? nn1W[c * (D_IN * H1) + i * H1 + o] : nn1b[i * H1 + o];
    _Float16 hv = (_Float16)v;
    Wfrag[tid] = __builtin_bit_cast(unsigned short, hv);
  } else if (tid < 544 * 112 + H1 * 340) {
    const int idx = tid - 544 * 112;
    const int i = idx / 340, j = idx % 340;
    const int k = j / H2, o = j % H2;
    Bext[idx] = (k < 16) ? nn2W[k * (H1 * H2) + i * H2 + o] : nn2b[i * H2 + o];
  }
  // zero accumulators: 2,410,000 floats = 602,500 float4
  float4* zp = (float4*)zbase;
  for (int i = tid; i < 602500; i += 512 * 256)
    zp[i] = make_float4(0.f, 0.f, 0.f, 0.f);
}

// ---------------------------------------------------------------------------
// Layer 1 edge messages via fp16 MFMA, EB=64:
//   msg[e,o] = sum_j P[e,j]*W'[j,o],  P[e,c*32+i] = ea[e,c]*x[src[e],i] (c=16: ea=1)
// Block: 256 thr = 4 waves, 64 edges = 4 e-tiles; wave w owns tile w (7 MFMA/c).
// B-fragments staged once per block into double-buffered LDS (shared by waves);
// P is wave-private (no barrier needed for it); one barrier per c-chunk.
// ---------------------------------------------------------------------------
__global__ __launch_bounds__(256, 2) void edge1_kernel(
    const float* __restrict__ x, const float* __restrict__ ea,
    const int* __restrict__ eidx, const unsigned short* __restrict__ Wfrag,
    float* __restrict__ agg1)
{
  __shared__ uint4 Plds[4 * 64];       // [tile][lane] A-fragments (wave-private)
  __shared__ uint4 Blds[2][7 * 64];    // double-buffered B-fragments
  __shared__ int   sdst[EB1];

  const int t    = threadIdx.x;
  const int lane = t & 63;
  const int w    = t >> 6;
  const int e0   = blockIdx.x * EB1;   // 625 * 64 = 40000 exact, no guards

  // thread t: edge e_loc = t>>2, j-octet jg = t&3 (8 x-features)
  const int e_loc = t >> 2;
  const int jg    = t & 3;
  const int src   = eidx[e0 + e_loc];

  h2f xh[4];   // 8 fp16 x-features of this octet
  {
    const float4* xp = (const float4*)&x[(size_t)src * D_IN + jg * 8];
    float4 v0 = xp[0], v1 = xp[1];
    float xf[8] = {v0.x, v0.y, v0.z, v0.w, v1.x, v1.y, v1.z, v1.w};
    #pragma unroll
    for (int j = 0; j < 4; ++j) {
      h2f p; p[0] = (_Float16)xf[2*j]; p[1] = (_Float16)xf[2*j+1]; xh[j] = p;
    }
  }
  _Float16 eh[17];
  {
    const float4* ep = (const float4*)&ea[(size_t)(e0 + e_loc) * D_E];
    float4 v0 = ep[0], v1 = ep[1], v2 = ep[2], v3 = ep[3];
    float ef[16] = {v0.x,v0.y,v0.z,v0.w, v1.x,v1.y,v1.z,v1.w,
                    v2.x,v2.y,v2.z,v2.w, v3.x,v3.y,v3.z,v3.w};
    #pragma unroll
    for (int k = 0; k < 16; ++k) eh[k] = (_Float16)ef[k];
    eh[16] = (_Float16)1.0f;
  }
  if (t < EB1) sdst[t] = eidx[N_EDGES + e0 + t];

  const uint4* __restrict__ Bf = (const uint4*)Wfrag;

  // stage B chunk 0 into buffer 0 (448 uint4, 256 threads -> t and 256+t)
  {
    uint4 s0 = Bf[t];
    uint4 s1;
    if (t < 192) s1 = Bf[256 + t];
    Blds[0][t] = s0;
    if (t < 192) Blds[0][256 + t] = s1;
  }
  __syncthreads();

  f4 acc[7];
  #pragma unroll
  for (int to = 0; to < 7; ++to) acc[to] = f4{0.f, 0.f, 0.f, 0.f};

  const int pslot = w * 64 + (e_loc & 15) + 16 * jg;

  #pragma unroll
  for (int c = 0; c < 17; ++c) {
    // prefetch next B chunk (reg-staged; latency hidden under MFMAs)
    uint4 s0, s1;
    if (c < 16) {
      const uint4* bn = Bf + (c + 1) * 448;
      s0 = bn[t];
      if (t < 192) s1 = bn[256 + t];
    }

    // P-generation for chunk c (8 fp16 products -> one 16-B A-frag write)
    h2f es; es[0] = eh[c]; es[1] = eh[c];
    unsigned int pk[4];
    #pragma unroll
    for (int j = 0; j < 4; ++j) {
      h2f pr = xh[j] * es;
      pk[j] = __builtin_bit_cast(unsigned int, pr);
    }
    Plds[pslot] = make_uint4(pk[0], pk[1], pk[2], pk[3]);

    uint4 a = Plds[w * 64 + lane];   // own-wave data (lgkmcnt-ordered)
    h8f A = __builtin_bit_cast(h8f, a);

    const uint4* bb = &Blds[c & 1][0];
    #pragma unroll
    for (int to = 0; to < 7; ++to) {
      h8f B = __builtin_bit_cast(h8f, bb[to * 64 + lane]);
      acc[to] = __builtin_amdgcn_mfma_f32_16x16x32_f16(A, B, acc[to], 0, 0, 0);
    }

    if (c < 16) {
      Blds[(c + 1) & 1][t] = s0;
      if (t < 192) Blds[(c + 1) & 1][256 + t] = s1;
    }
    __syncthreads();   // publish B[c+1]; everyone done reading B[c]
  }

  // epilogue: coalesced atomics (lanes 0..15 = 16 consecutive o)
  const int col = lane & 15, rowg = lane >> 4;
  #pragma unroll
  for (int r = 0; r < 4; ++r) {
    const int el = w * 16 + rowg * 4 + r;
    const int d = sdst[el];
    float* ap = agg1 + (size_t)d * H1;
    #pragma unroll
    for (int to = 0; to < 7; ++to) {
      const int o = to * 16 + col;
      if (o < H1) atomicAdd(&ap[o], acc[to][r]);
    }
  }
}

// ---------------------------------------------------------------------------
// Fused node1 + Y2 GEMM:
//   h1[n,i] = relu(agg1[n,i] + sum_d x[n,d]*root1[d,i] + bias1[i])   (also stored)
//   Y2[n,j] = sum_i h1[n,i] * Bext[i,j]
// thread owns 4n x 4j = 16 acc; block = 12 nodes x 340 cols
// ---------------------------------------------------------------------------
__global__ __launch_bounds__(256) void y2h1_kernel(
    const float* __restrict__ x, const float* __restrict__ agg1,
    const float* __restrict__ root1, const float* __restrict__ bias1,
    const float* __restrict__ Bext, float* __restrict__ h1,
    float* __restrict__ Y2)
{
  __shared__ float sroot1[D_IN * H1];                 // 12.8 KB, [d*100+i]
  __shared__ float sxl[YNB * D_IN];                   // [nn*32+d]
  __shared__ __align__(16) float hT[H1][YNB];
  const int t  = threadIdx.x;
  const int n0 = blockIdx.x * YNB;

  for (int idx = t; idx < 800; idx += 256)
    *(float4*)&sroot1[idx * 4] = *(const float4*)&root1[idx * 4];
  if (t < 96) {
    const int fo = t * 4;
    const int nn = fo >> 5;
    float4 v = make_float4(0.f, 0.f, 0.f, 0.f);
    if (n0 + nn < N_NODES) v = *(const float4*)&x[(size_t)n0 * D_IN + fo];
    *(float4*)&sxl[fo] = v;
  }
  __syncthreads();

  // compute h1 for this block's 12 nodes (write global + LDS-transposed)
  for (int idx = t; idx < YNB * H1; idx += 256) {
    const int nn = idx / H1, i = idx - nn * H1;
    const int n = n0 + nn;
    float v = 0.f;
    if (n < N_NODES) {
      v = agg1[(size_t)n0 * H1 + idx] + bias1[i];
      #pragma unroll 8
      for (int d = 0; d < D_IN; ++d)
        v = fmaf(sxl[nn * D_IN + d], sroot1[d * H1 + i], v);
      v = fmaxf(v, 0.f);
      h1[(size_t)n0 * H1 + idx] = v;
    }
    hT[i][nn] = v;
  }
  __syncthreads();

  const int jg = t % 85;     // j0 = 4*jg : lanes contiguous in j -> coalesced
  const int ng = t / 85;     // 0..2 active
  if (ng < 3) {
    const int j0 = jg * 4;
    const float* __restrict__ bp = Bext + j0;
    float acc[4][4];
    #pragma unroll
    for (int r = 0; r < 4; ++r)
      #pragma unroll
      for (int cc = 0; cc < 4; ++cc) acc[r][cc] = 0.f;

    #pragma unroll 2
    for (int i = 0; i < H1; ++i) {
      const float4 bv = *(const float4*)&bp[i * 340];
      const float4 hv = *(const float4*)&hT[i][ng * 4];   // broadcast read
      acc[0][0] = fmaf(hv.x, bv.x, acc[0][0]);
      acc[0][1] = fmaf(hv.x, bv.y, acc[0][1]);
      acc[0][2] = fmaf(hv.x, bv.z, acc[0][2]);
      acc[0][3] = fmaf(hv.x, bv.w, acc[0][3]);
      acc[1][0] = fmaf(hv.y, bv.x, acc[1][0]);
      acc[1][1] = fmaf(hv.y, bv.y, acc[1][1]);
      acc[1][2] = fmaf(hv.y, bv.z, acc[1][2]);
      acc[1][3] = fmaf(hv.y, bv.w, acc[1][3]);
      acc[2][0] = fmaf(hv.z, bv.x, acc[2][0]);
      acc[2][1] = fmaf(hv.z, bv.y, acc[2][1]);
      acc[2][2] = fmaf(hv.z, bv.z, acc[2][2]);
      acc[2][3] = fmaf(hv.z, bv.w, acc[2][3]);
      acc[3][0] = fmaf(hv.w, bv.x, acc[3][0]);
      acc[3][1] = fmaf(hv.w, bv.y, acc[3][1]);
      acc[3][2] = fmaf(hv.w, bv.z, acc[3][2]);
      acc[3][3] = fmaf(hv.w, bv.w, acc[3][3]);
    }
    const int nb = n0 + ng * 4;
    #pragma unroll
    for (int r = 0; r < 4; ++r) {
      const int n = nb + r;
      if (n < N_NODES)
        *(float4*)&Y2[(size_t)n * 340 + j0] =
            make_float4(acc[r][0], acc[r][1], acc[r][2], acc[r][3]);
    }
  }
}

// ---------------------------------------------------------------------------
// Layer 2 edge pass with LDS row staging:
//   msg2[e,o] = Y2[src,320+o] + sum_k ea[e,k]*Y2[src,k*20+o]
// ---------------------------------------------------------------------------
__global__ __launch_bounds__(256) void edge2_kernel(
    const float* __restrict__ ea, const int* __restrict__ eidx,
    const float* __restrict__ Y2, float* __restrict__ agg2)
{
  __shared__ __align__(16) float sy[ET3][344];
  __shared__ float se[ET3][16];
  __shared__ int sd[ET3];
  const int t  = threadIdx.x;
  const int e0 = blockIdx.x * ET3;

  if (t < ET3) {
    const int e = e0 + t;
    sd[t] = (e < N_EDGES) ? eidx[N_EDGES + e] : -1;
  }
  for (int idx = t; idx < ET3 * 4; idx += 256) {
    const int el = idx >> 2, q = idx & 3;
    const int e = e0 + el;
    if (e < N_EDGES)
      *(float4*)&se[el][q * 4] = *(const float4*)&ea[(size_t)e * D_E + q * 4];
  }
  for (int idx = t; idx < ET3 * 85; idx += 256) {
    const int el = idx / 85, q = idx - el * 85;
    const int e = e0 + el;
    if (e < N_EDGES) {
      const int s = eidx[e];
      *(float4*)&sy[el][q * 4] = *(const float4*)&Y2[(size_t)s * 340 + q * 4];
    }
  }
  __syncthreads();

  const int el = t / H2, o = t % H2;
  const int e = e0 + el;
  if (el < ET3 && e < N_EDGES) {
    float m = sy[el][320 + o];
    #pragma unroll
    for (int k = 0; k < D_E; ++k)
      m = fmaf(se[el][k], sy[el][k * 20 + o], m);
    atomicAdd(&agg2[(size_t)sd[el] * H2 + o], m);
  }
}

// ---------------------------------------------------------------------------
// Fused node update 2 + sum-pool (batch sorted -> run-length reduce)
// ---------------------------------------------------------------------------
__global__ __launch_bounds__(256) void node2_pool_kernel(
    const float* __restrict__ h1, const float* __restrict__ agg2,
    const float* __restrict__ root2, const float* __restrict__ bias2,
    const int* __restrict__ batch, float* __restrict__ g)
{
  __shared__ float sroot[H1 * H2];
  __shared__ float sv[ET3][H2];
  __shared__ int   sg[ET3];
  const int t  = threadIdx.x;
  const int n0 = blockIdx.x * ET3;

  for (int idx = t; idx < (H1 * H2) / 4; idx += 256)
    *(float4*)&sroot[idx * 4] = *(const float4*)&root2[idx * 4];
  if (t < ET3) {
    const int n = n0 + t;
    sg[t] = (n < N_NODES) ? batch[n] : -1;
  }
  __syncthreads();

  const int nl = t / H2, o = t % H2;
  const int n = n0 + nl;
  if (nl < ET3) {
    float v = 0.f;
    if (n < N_NODES) {
      v = agg2[(size_t)n * H2 + o] + bias2[o];
      const float* hr = &h1[(size_t)n * H1];
      #pragma unroll 5
      for (int i = 0; i < H1; i += 4) {
        const float4 hv = *(const float4*)&hr[i];
        v = fmaf(hv.x, sroot[(i    ) * H2 + o], v);
        v = fmaf(hv.y, sroot[(i + 1) * H2 + o], v);
        v = fmaf(hv.z, sroot[(i + 2) * H2 + o], v);
        v = fmaf(hv.w, sroot[(i + 3) * H2 + o], v);
      }
      v = fmaxf(v, 0.f);
    }
    sv[nl][o] = v;
  }
  __syncthreads();

  if (t < H2) {
    float run = 0.f;
    int cur = sg[0];
    #pragma unroll
    for (int r = 0; r < ET3; ++r) {
      const int gid = sg[r];
      if (gid != cur) {
        if (cur >= 0) atomicAdd(&g[cur * H2 + t], run);
        run = 0.f; cur = gid;
      }
      run += sv[r][t];
    }
    if (cur >= 0) atomicAdd(&g[cur * H2 + t], run);
  }
}

// ---------------------------------------------------------------------------
// Final MLP
// ---------------------------------------------------------------------------
__global__ __launch_bounds__(64) void final_kernel(
    const float* __restrict__ g, const float* __restrict__ lin1W,
    const float* __restrict__ lin1b, const float* __restrict__ lin2W,
    const float* __restrict__ lin2b, float* __restrict__ out)
{
  const int gr = blockIdx.x;
  const int tt = threadIdx.x;
  float v = 0.f;
  if (tt < F1) {
    float s = lin1b[tt];
    #pragma unroll
    for (int o = 0; o < H2; ++o) s = fmaf(g[gr * H2 + o], lin1W[o * F1 + tt], s);
    v = fmaxf(s, 0.f) * lin2W[tt];
  }
  #pragma unroll
  for (int off = 32; off > 0; off >>= 1) v += __shfl_down(v, off, 64);
  if (tt == 0) out[gr] = v + lin2b[0];
}

extern "C" void kernel_launch(void* const* d_in, const int* in_sizes, int n_in,
                              void* d_out, int out_size, void* d_ws, size_t ws_size,
                              hipStream_t stream) {
  const float* x     = (const float*)d_in[0];
  const float* ea    = (const float*)d_in[1];
  const int*   eidx  = (const int*)d_in[2];
  const int*   batch = (const int*)d_in[3];
  const float* nn1W  = (const float*)d_in[4];
  const float* nn1b  = (const float*)d_in[5];
  const float* root1 = (const float*)d_in[6];
  const float* bias1 = (const float*)d_in[7];
  const float* nn2W  = (const float*)d_in[8];
  const float* nn2b  = (const float*)d_in[9];
  const float* root2 = (const float*)d_in[10];
  const float* bias2 = (const float*)d_in[11];
  const float* lin1W = (const float*)d_in[12];
  const float* lin1b = (const float*)d_in[13];
  const float* lin2W = (const float*)d_in[14];
  const float* lin2b = (const float*)d_in[15];
  float* out = (float*)d_out;

  float* ws   = (float*)d_ws;
  float* agg1 = ws;                          // 2,000,000 floats
  float* agg2 = agg1 + N_NODES * H1;         //   400,000
  float* g    = agg2 + N_NODES * H2;         //    10,000
  float* h1   = g    + N_GRAPHS * H2;        // 2,000,000
  float* spare= h1   + N_NODES * H1;         //   400,000
  float* Y2   = spare+ N_NODES * H2;         // 6,800,000
  // aliases (consumed before their hosts are written):
  float* Bext = spare;                                       // 34,000 < 400,000
  unsigned short* Wfrag = (unsigned short*)(Y2 + (size_t)N_NODES * 340 - 30464);

  prep_kernel<<<512, 256, 0, stream>>>(nn1W, nn1b, nn2W, nn2b, Wfrag, Bext, agg1);
  edge1_kernel<<<N_EDGES / EB1, 256, 0, stream>>>(x, ea, eidx, Wfrag, agg1);
  y2h1_kernel<<<(N_NODES + YNB - 1) / YNB, 256, 0, stream>>>(
      x, agg1, root1, bias1, Bext, h1, Y2);
  edge2_kernel<<<(N_EDGES + ET3 - 1) / ET3, 256, 0, stream>>>(ea, eidx, Y2, agg2);
  node2_pool_kernel<<<(N_NODES + ET3 - 1) / ET3, 256, 0, stream>>>(
      h1, agg2, root2, bias2, batch, g);
  final_kernel<<<N_GRAPHS, 64, 0, stream>>>(g, lin1W, lin1b, lin2W, lin2b, out);
}

// Round 6
// 172.753 us; speedup vs baseline: 2.9843x; 1.0577x over previous
//
#include <hip/hip_runtime.h>
#include <hip/hip_bf16.h>
#include <hip/hip_fp16.h>

#define N_NODES 20000
#define N_EDGES 40000
#define N_GRAPHS 500
#define D_IN 32
#define D_E 16
#define H1 100
#define H2 20
#define F1 50

#define EB1 64    // edges per block, MFMA kernels
#define YNB 12    // nodes per block, node1
#define ET3 12    // nodes per block, node2_pool

using h2f = __attribute__((ext_vector_type(2))) _Float16;
using h8f = __attribute__((ext_vector_type(8))) _Float16;
using f4  = __attribute__((ext_vector_type(4))) float;

// ---------------------------------------------------------------------------
// prep: (a) Wfrag1: layer-1 W' -> per-lane MFMA fragment order (fp16)
//   W1'[c*32+i][o] = (c<16 ? nn1W[c*3200+i*100+o] : nn1b[i*100+o]), o<100 else 0
//   Wfrag1[((c*7+to)*64+l)*8+j] = W1'[c*32+(l>>4)*8+j][to*16+(l&15)]
// (b) Wfrag2: layer-2 W2' fragments (fp16), K padded 100->128 per chunk:
//   W2'[c*128+i][o] = (i<100 && o<20) ? (c<16 ? nn2W[c*2000+i*20+o] : nn2b[i*20+o]) : 0
//   Wfrag2[(((c*4+q)*2+to)*64+l)*8+j] = W2'[c*128+q*32+(l>>4)*8+j][to*16+(l&15)]
// (c) zero agg1|agg2|g (2,410,000 floats contiguous)
// ---------------------------------------------------------------------------
__global__ __launch_bounds__(256) void prep_kernel(
    const float* __restrict__ nn1W, const float* __restrict__ nn1b,
    const float* __restrict__ nn2W, const float* __restrict__ nn2b,
    unsigned short* __restrict__ Wfrag1, unsigned short* __restrict__ Wfrag2,
    float* __restrict__ zbase)
{
  const int tid = blockIdx.x * 256 + threadIdx.x;
  if (tid < 544 * 112) {
    const int c  = tid / 3584;
    const int r  = tid % 3584;
    const int to = r / 512;
    const int l  = (r % 512) >> 3;
    const int j  = r & 7;
    const int i  = (l >> 4) * 8 + j;
    const int o  = to * 16 + (l & 15);
    float v = 0.f;
    if (o < H1) v = (c < 16) ? nn1W[c * (D_IN * H1) + i * H1 + o] : nn1b[i * H1 + o];
    _Float16 hv = (_Float16)v;
    Wfrag1[tid] = __builtin_bit_cast(unsigned short, hv);
  } else if (tid < 544 * 112 + 17 * 4096) {
    const int t2 = tid - 544 * 112;
    const int c  = t2 >> 12;
    const int q  = (t2 >> 10) & 3;
    const int to = (t2 >> 9) & 1;
    const int l  = (t2 >> 3) & 63;
    const int j  = t2 & 7;
    const int i  = q * 32 + (l >> 4) * 8 + j;
    const int o  = to * 16 + (l & 15);
    float v = 0.f;
    if (i < H1 && o < H2)
      v = (c < 16) ? nn2W[c * (H1 * H2) + i * H2 + o] : nn2b[i * H2 + o];
    _Float16 hv = (_Float16)v;
    Wfrag2[t2] = __builtin_bit_cast(unsigned short, hv);
  }
  // zero accumulators: 2,410,000 floats = 602,500 float4
  float4* zp = (float4*)zbase;
  for (int i = tid; i < 602500; i += 512 * 256)
    zp[i] = make_float4(0.f, 0.f, 0.f, 0.f);
}

// ---------------------------------------------------------------------------
// Layer 1 edge messages via fp16 MFMA (unchanged, verified):
//   msg[e,o] = sum_j P[e,j]*W1'[j,o],  P[e,c*32+i] = ea[e,c]*x[src[e],i]
// ---------------------------------------------------------------------------
__global__ __launch_bounds__(256, 2) void edge1_kernel(
    const float* __restrict__ x, const float* __restrict__ ea,
    const int* __restrict__ eidx, const unsigned short* __restrict__ Wfrag,
    float* __restrict__ agg1)
{
  __shared__ uint4 Plds[4 * 64];
  __shared__ uint4 Blds[2][7 * 64];
  __shared__ int   sdst[EB1];

  const int t    = threadIdx.x;
  const int lane = t & 63;
  const int w    = t >> 6;
  const int e0   = blockIdx.x * EB1;

  const int e_loc = t >> 2;
  const int jg    = t & 3;
  const int src   = eidx[e0 + e_loc];

  h2f xh[4];
  {
    const float4* xp = (const float4*)&x[(size_t)src * D_IN + jg * 8];
    float4 v0 = xp[0], v1 = xp[1];
    float xf[8] = {v0.x, v0.y, v0.z, v0.w, v1.x, v1.y, v1.z, v1.w};
    #pragma unroll
    for (int j = 0; j < 4; ++j) {
      h2f p; p[0] = (_Float16)xf[2*j]; p[1] = (_Float16)xf[2*j+1]; xh[j] = p;
    }
  }
  _Float16 eh[17];
  {
    const float4* ep = (const float4*)&ea[(size_t)(e0 + e_loc) * D_E];
    float4 v0 = ep[0], v1 = ep[1], v2 = ep[2], v3 = ep[3];
    float ef[16] = {v0.x,v0.y,v0.z,v0.w, v1.x,v1.y,v1.z,v1.w,
                    v2.x,v2.y,v2.z,v2.w, v3.x,v3.y,v3.z,v3.w};
    #pragma unroll
    for (int k = 0; k < 16; ++k) eh[k] = (_Float16)ef[k];
    eh[16] = (_Float16)1.0f;
  }
  if (t < EB1) sdst[t] = eidx[N_EDGES + e0 + t];

  const uint4* __restrict__ Bf = (const uint4*)Wfrag;

  {
    uint4 s0 = Bf[t];
    uint4 s1;
    if (t < 192) s1 = Bf[256 + t];
    Blds[0][t] = s0;
    if (t < 192) Blds[0][256 + t] = s1;
  }
  __syncthreads();

  f4 acc[7];
  #pragma unroll
  for (int to = 0; to < 7; ++to) acc[to] = f4{0.f, 0.f, 0.f, 0.f};

  const int pslot = w * 64 + (e_loc & 15) + 16 * jg;

  #pragma unroll
  for (int c = 0; c < 17; ++c) {
    uint4 s0, s1;
    if (c < 16) {
      const uint4* bn = Bf + (c + 1) * 448;
      s0 = bn[t];
      if (t < 192) s1 = bn[256 + t];
    }

    h2f es; es[0] = eh[c]; es[1] = eh[c];
    unsigned int pk[4];
    #pragma unroll
    for (int j = 0; j < 4; ++j) {
      h2f pr = xh[j] * es;
      pk[j] = __builtin_bit_cast(unsigned int, pr);
    }
    Plds[pslot] = make_uint4(pk[0], pk[1], pk[2], pk[3]);

    uint4 a = Plds[w * 64 + lane];
    h8f A = __builtin_bit_cast(h8f, a);

    const uint4* bb = &Blds[c & 1][0];
    #pragma unroll
    for (int to = 0; to < 7; ++to) {
      h8f B = __builtin_bit_cast(h8f, bb[to * 64 + lane]);
      acc[to] = __builtin_amdgcn_mfma_f32_16x16x32_f16(A, B, acc[to], 0, 0, 0);
    }

    if (c < 16) {
      Blds[(c + 1) & 1][t] = s0;
      if (t < 192) Blds[(c + 1) & 1][256 + t] = s1;
    }
    __syncthreads();
  }

  const int col = lane & 15, rowg = lane >> 4;
  #pragma unroll
  for (int r = 0; r < 4; ++r) {
    const int el = w * 16 + rowg * 4 + r;
    const int d = sdst[el];
    float* ap = agg1 + (size_t)d * H1;
    #pragma unroll
    for (int to = 0; to < 7; ++to) {
      const int o = to * 16 + col;
      if (o < H1) atomicAdd(&ap[o], acc[to][r]);
    }
  }
}

// ---------------------------------------------------------------------------
// Node update 1: h1 = relu(agg1 + x @ root1 + bias1), 12 nodes/block
// ---------------------------------------------------------------------------
__global__ __launch_bounds__(256) void node1_kernel(
    const float* __restrict__ x, const float* __restrict__ agg1,
    const float* __restrict__ root1, const float* __restrict__ bias1,
    float* __restrict__ h1)
{
  __shared__ float sroot1[D_IN * H1];
  __shared__ float sxl[YNB * D_IN];
  const int t  = threadIdx.x;
  const int n0 = blockIdx.x * YNB;

  for (int idx = t; idx < 800; idx += 256)
    *(float4*)&sroot1[idx * 4] = *(const float4*)&root1[idx * 4];
  if (t < 96) {
    const int fo = t * 4;
    const int nn = fo >> 5;
    float4 v = make_float4(0.f, 0.f, 0.f, 0.f);
    if (n0 + nn < N_NODES) v = *(const float4*)&x[(size_t)n0 * D_IN + fo];
    *(float4*)&sxl[fo] = v;
  }
  __syncthreads();

  for (int idx = t; idx < YNB * H1; idx += 256) {
    const int nn = idx / H1, i = idx - nn * H1;
    const int n = n0 + nn;
    if (n < N_NODES) {
      float v = agg1[(size_t)n0 * H1 + idx] + bias1[i];
      #pragma unroll 8
      for (int d = 0; d < D_IN; ++d)
        v = fmaf(sxl[nn * D_IN + d], sroot1[d * H1 + i], v);
      h1[(size_t)n0 * H1 + idx] = fmaxf(v, 0.f);
    }
  }
}

// ---------------------------------------------------------------------------
// Layer 2 edge messages via fp16 MFMA:
//   msg2[e,o] = sum_j P2[e,j]*W2'[j,o], P2[e,c*128+i] = ea[e,c]*h1[src[e],i]
// 64 edges/block, 4 waves; wave w owns e-tile w (16 edges) x 2 N-tiles.
// 17 chunks x 4 K-steps of 32; B double-buffered per chunk; A wave-private.
// ---------------------------------------------------------------------------
__global__ __launch_bounds__(256, 2) void edge2m_kernel(
    const float* __restrict__ h1, const float* __restrict__ ea,
    const int* __restrict__ eidx, const unsigned short* __restrict__ Wfrag2,
    float* __restrict__ agg2)
{
  __shared__ uint4 Plds[4][4][64];   // [wave][q][16*oct + edge], wave-private
  __shared__ uint4 Blds[2][512];     // [buf][q*128 + to*64 + lane]
  __shared__ int   sdst[EB1];

  const int t    = threadIdx.x;
  const int lane = t & 63;
  const int w    = t >> 6;
  const int e0   = blockIdx.x * EB1;   // 625*64 = 40000 exact

  const int e_loc = t >> 2;    // wave w's threads cover edges [16w,16w+16)
  const int jg    = t & 3;     // feature quarter: i in [32*jg, 32*jg+32)
  const int m     = e_loc & 15;
  const int src   = eidx[e0 + e_loc];

  // 32 h1 features (pad >=100 with zeros), fp16 pairs
  h2f xh[16];
  {
    float xf[32];
    const float* hp = &h1[(size_t)src * H1 + jg * 32];
    if (jg < 3) {
      #pragma unroll
      for (int q4 = 0; q4 < 8; ++q4) {
        float4 v = *(const float4*)&hp[q4 * 4];
        xf[q4*4+0] = v.x; xf[q4*4+1] = v.y; xf[q4*4+2] = v.z; xf[q4*4+3] = v.w;
      }
    } else {
      float4 v = *(const float4*)hp;   // features 96..99
      xf[0] = v.x; xf[1] = v.y; xf[2] = v.z; xf[3] = v.w;
      #pragma unroll
      for (int ii = 4; ii < 32; ++ii) xf[ii] = 0.f;
    }
    #pragma unroll
    for (int j2 = 0; j2 < 16; ++j2) {
      h2f p; p[0] = (_Float16)xf[2*j2]; p[1] = (_Float16)xf[2*j2+1]; xh[j2] = p;
    }
  }
  _Float16 eh[17];
  {
    const float4* ep = (const float4*)&ea[(size_t)(e0 + e_loc) * D_E];
    float4 v0 = ep[0], v1 = ep[1], v2 = ep[2], v3 = ep[3];
    float ef[16] = {v0.x,v0.y,v0.z,v0.w, v1.x,v1.y,v1.z,v1.w,
                    v2.x,v2.y,v2.z,v2.w, v3.x,v3.y,v3.z,v3.w};
    #pragma unroll
    for (int k = 0; k < 16; ++k) eh[k] = (_Float16)ef[k];
    eh[16] = (_Float16)1.0f;
  }
  if (t < EB1) sdst[t] = eidx[N_EDGES + e0 + t];

  const uint4* __restrict__ Bf = (const uint4*)Wfrag2;

  // stage chunk 0 B-frags (512 uint4) + chunk 0 P-frags
  {
    uint4 s0 = Bf[t];
    uint4 s1 = Bf[256 + t];
    Blds[0][t] = s0;
    Blds[0][256 + t] = s1;
  }
  {
    h2f es; es[0] = eh[0]; es[1] = eh[0];
    unsigned int pk[16];
    #pragma unroll
    for (int j2 = 0; j2 < 16; ++j2) {
      h2f pr = xh[j2] * es;
      pk[j2] = __builtin_bit_cast(unsigned int, pr);
    }
    #pragma unroll
    for (int oc = 0; oc < 4; ++oc)
      Plds[w][jg][16 * oc + m] = make_uint4(pk[4*oc], pk[4*oc+1], pk[4*oc+2], pk[4*oc+3]);
  }
  __syncthreads();

  f4 acc0 = f4{0.f, 0.f, 0.f, 0.f};
  f4 acc1 = f4{0.f, 0.f, 0.f, 0.f};

  #pragma unroll
  for (int c = 0; c < 17; ++c) {
    const int buf = c & 1;
    // prefetch next chunk's B-frags
    uint4 s0, s1;
    if (c < 16) {
      const uint4* bn = Bf + (c + 1) * 512;
      s0 = bn[t];
      s1 = bn[256 + t];
    }

    // 4 K-steps of this chunk
    #pragma unroll
    for (int q = 0; q < 4; ++q) {
      uint4 a  = Plds[w][q][lane];
      uint4 b0 = Blds[buf][q * 128 + lane];
      uint4 b1 = Blds[buf][q * 128 + 64 + lane];
      h8f A  = __builtin_bit_cast(h8f, a);
      h8f B0 = __builtin_bit_cast(h8f, b0);
      h8f B1 = __builtin_bit_cast(h8f, b1);
      acc0 = __builtin_amdgcn_mfma_f32_16x16x32_f16(A, B0, acc0, 0, 0, 0);
      acc1 = __builtin_amdgcn_mfma_f32_16x16x32_f16(A, B1, acc1, 0, 0, 0);
    }

    if (c < 16) {
      // P-gen for chunk c+1 (own-wave LDS; reads above already issued)
      h2f es; es[0] = eh[c + 1]; es[1] = eh[c + 1];
      unsigned int pk[16];
      #pragma unroll
      for (int j2 = 0; j2 < 16; ++j2) {
        h2f pr = xh[j2] * es;
        pk[j2] = __builtin_bit_cast(unsigned int, pr);
      }
      #pragma unroll
      for (int oc = 0; oc < 4; ++oc)
        Plds[w][jg][16 * oc + m] = make_uint4(pk[4*oc], pk[4*oc+1], pk[4*oc+2], pk[4*oc+3]);
      // publish next B buffer
      Blds[buf ^ 1][t] = s0;
      Blds[buf ^ 1][256 + t] = s1;
      __syncthreads();
    }
  }

  // epilogue: C row=(lane>>4)*4+r = edge, col=lane&15 = o
  const int col = lane & 15, rowg = lane >> 4;
  #pragma unroll
  for (int r = 0; r < 4; ++r) {
    const int el = w * 16 + rowg * 4 + r;
    const int d  = sdst[el];
    float* ap = agg2 + (size_t)d * H2;
    atomicAdd(&ap[col], acc0[r]);              // o = col (0..15)
    if (col < 4) atomicAdd(&ap[16 + col], acc1[r]);   // o = 16..19
  }
}

// ---------------------------------------------------------------------------
// Fused node update 2 + sum-pool (batch sorted -> run-length reduce)
// ---------------------------------------------------------------------------
__global__ __launch_bounds__(256) void node2_pool_kernel(
    const float* __restrict__ h1, const float* __restrict__ agg2,
    const float* __restrict__ root2, const float* __restrict__ bias2,
    const int* __restrict__ batch, float* __restrict__ g)
{
  __shared__ float sroot[H1 * H2];
  __shared__ float sv[ET3][H2];
  __shared__ int   sg[ET3];
  const int t  = threadIdx.x;
  const int n0 = blockIdx.x * ET3;

  for (int idx = t; idx < (H1 * H2) / 4; idx += 256)
    *(float4*)&sroot[idx * 4] = *(const float4*)&root2[idx * 4];
  if (t < ET3) {
    const int n = n0 + t;
    sg[t] = (n < N_NODES) ? batch[n] : -1;
  }
  __syncthreads();

  const int nl = t / H2, o = t % H2;
  const int n = n0 + nl;
  if (nl < ET3) {
    float v = 0.f;
    if (n < N_NODES) {
      v = agg2[(size_t)n * H2 + o] + bias2[o];
      const float* hr = &h1[(size_t)n * H1];
      #pragma unroll 5
      for (int i = 0; i < H1; i += 4) {
        const float4 hv = *(const float4*)&hr[i];
        v = fmaf(hv.x, sroot[(i    ) * H2 + o], v);
        v = fmaf(hv.y, sroot[(i + 1) * H2 + o], v);
        v = fmaf(hv.z, sroot[(i + 2) * H2 + o], v);
        v = fmaf(hv.w, sroot[(i + 3) * H2 + o], v);
      }
      v = fmaxf(v, 0.f);
    }
    sv[nl][o] = v;
  }
  __syncthreads();

  if (t < H2) {
    float run = 0.f;
    int cur = sg[0];
    #pragma unroll
    for (int r = 0; r < ET3; ++r) {
      const int gid = sg[r];
      if (gid != cur) {
        if (cur >= 0) atomicAdd(&g[cur * H2 + t], run);
        run = 0.f; cur = gid;
      }
      run += sv[r][t];
    }
    if (cur >= 0) atomicAdd(&g[cur * H2 + t], run);
  }
}

// ---------------------------------------------------------------------------
// Final MLP
// ---------------------------------------------------------------------------
__global__ __launch_bounds__(64) void final_kernel(
    const float* __restrict__ g, const float* __restrict__ lin1W,
    const float* __restrict__ lin1b, const float* __restrict__ lin2W,
    const float* __restrict__ lin2b, float* __restrict__ out)
{
  const int gr = blockIdx.x;
  const int tt = threadIdx.x;
  float v = 0.f;
  if (tt < F1) {
    float s = lin1b[tt];
    #pragma unroll
    for (int o = 0; o < H2; ++o) s = fmaf(g[gr * H2 + o], lin1W[o * F1 + tt], s);
    v = fmaxf(s, 0.f) * lin2W[tt];
  }
  #pragma unroll
  for (int off = 32; off > 0; off >>= 1) v += __shfl_down(v, off, 64);
  if (tt == 0) out[gr] = v + lin2b[0];
}

extern "C" void kernel_launch(void* const* d_in, const int* in_sizes, int n_in,
                              void* d_out, int out_size, void* d_ws, size_t ws_size,
                              hipStream_t stream) {
  const float* x     = (const float*)d_in[0];
  const float* ea    = (const float*)d_in[1];
  const int*   eidx  = (const int*)d_in[2];
  const int*   batch = (const int*)d_in[3];
  const float* nn1W  = (const float*)d_in[4];
  const float* nn1b  = (const float*)d_in[5];
  const float* root1 = (const float*)d_in[6];
  const float* bias1 = (const float*)d_in[7];
  const float* nn2W  = (const float*)d_in[8];
  const float* nn2b  = (const float*)d_in[9];
  const float* root2 = (const float*)d_in[10];
  const float* bias2 = (const float*)d_in[11];
  const float* lin1W = (const float*)d_in[12];
  const float* lin1b = (const float*)d_in[13];
  const float* lin2W = (const float*)d_in[14];
  const float* lin2b = (const float*)d_in[15];
  float* out = (float*)d_out;

  float* ws   = (float*)d_ws;
  float* agg1 = ws;                          // 2,000,000 floats
  float* agg2 = agg1 + N_NODES * H1;         //   400,000
  float* g    = agg2 + N_NODES * H2;         //    10,000
  float* h1   = g    + N_GRAPHS * H2;        // 2,000,000
  unsigned short* Wfrag1 = (unsigned short*)(h1 + (size_t)N_NODES * H1);  // 60,928 u16
  unsigned short* Wfrag2 = Wfrag1 + 61440;                                // 69,632 u16

  prep_kernel<<<512, 256, 0, stream>>>(nn1W, nn1b, nn2W, nn2b, Wfrag1, Wfrag2, agg1);
  edge1_kernel<<<N_EDGES / EB1, 256, 0, stream>>>(x, ea, eidx, Wfrag1, agg1);
  node1_kernel<<<(N_NODES + YNB - 1) / YNB, 256, 0, stream>>>(
      x, agg1, root1, bias1, h1);
  edge2m_kernel<<<N_EDGES / EB1, 256, 0, stream>>>(h1, ea, eidx, Wfrag2, agg2);
  node2_pool_kernel<<<(N_NODES + ET3 - 1) / ET3, 256, 0, stream>>>(
      h1, agg2, root2, bias2, batch, g);
  final_kernel<<<N_GRAPHS, 64, 0, stream>>>(g, lin1W, lin1b, lin2W, lin2b, out);
}